// Round 2
// baseline (7917.435 us; speedup 1.0000x reference)
//
#include <hip/hip_runtime.h>
#include <hip/hip_bf16.h>
#include <stdint.h>

#define B_ 64
#define S_ 512
#define I_ 512
#define H_ 1024
#define NB 64          // blocks; block g owns 16 h-columns [16g, 16g+16)
#define HWORDS (B_ * H_)   // 65536 words per h buffer

typedef __attribute__((ext_vector_type(8))) __bf16 bf16x8;
typedef __attribute__((ext_vector_type(4))) float f32x4;
typedef __attribute__((ext_vector_type(4))) unsigned u32x4;

__device__ __forceinline__ unsigned short f2bf(float f) {
    unsigned u = __float_as_uint(f);
    u += 0x7FFFu + ((u >> 16) & 1u);   // RNE
    return (unsigned short)(u >> 16);
}

__device__ __forceinline__ bf16x8 ld8(const unsigned short* p) {
    return *(const bf16x8*)p;
}

// ---------- prep: convert x to bf16 ----------
__global__ __launch_bounds__(256) void gru_prep(const float* __restrict__ x,
                                                unsigned short* __restrict__ xbf) {
    const int NX = (B_ * S_ * I_) / 4;
    int stride = gridDim.x * blockDim.x;
    for (int i = blockIdx.x * blockDim.x + threadIdx.x; i < NX; i += stride) {
        float4 v = ((const float4*)x)[i];
        ushort4 o;
        o.x = f2bf(v.x); o.y = f2bf(v.y); o.z = f2bf(v.z); o.w = f2bf(v.w);
        ((ushort4*)xbf)[i] = o;
    }
}

// ---------- tagged-exchange: h words are (step_tag<<16)|bf16(h) ----------
// Round 7 change: ALL 64 h-loads issued at once from one base pointer using
// immediate offsets (0..3984B fits the 13-bit signed offset field), ONE
// vmcnt(0), then per-group tag validation between MFMA batches. This takes
// the h-phase from 4 serialized mall RTs (round 6: each group issued only
// after the previous validated) to 1 RT. Re-issue is the rare path, only for
// a group whose producers are late.
// L1/L2 bypass: sc0 sc1. Data valid only after s_waitcnt vmcnt(0)+sched_barrier.

#define LD16(dst, off) asm volatile(                                          \
    "global_load_dwordx4 %0, %1, off offset:" #off " sc0 sc1"                 \
    : "=v"(dst) : "v"(hb))

#define ISSUE_G0() do{ LD16(d0[0],0);    LD16(d0[1],16);   LD16(d0[2],128);  LD16(d0[3],144);  \
                       LD16(d0[4],256);  LD16(d0[5],272);  LD16(d0[6],384);  LD16(d0[7],400);  \
                       LD16(d0[8],512);  LD16(d0[9],528);  LD16(d0[10],640); LD16(d0[11],656); \
                       LD16(d0[12],768); LD16(d0[13],784); LD16(d0[14],896); LD16(d0[15],912); }while(0)
#define ISSUE_G1() do{ LD16(d1[0],1024); LD16(d1[1],1040); LD16(d1[2],1152); LD16(d1[3],1168); \
                       LD16(d1[4],1280); LD16(d1[5],1296); LD16(d1[6],1408); LD16(d1[7],1424); \
                       LD16(d1[8],1536); LD16(d1[9],1552); LD16(d1[10],1664);LD16(d1[11],1680);\
                       LD16(d1[12],1792);LD16(d1[13],1808);LD16(d1[14],1920);LD16(d1[15],1936);}while(0)
#define ISSUE_G2() do{ LD16(d2[0],2048); LD16(d2[1],2064); LD16(d2[2],2176); LD16(d2[3],2192); \
                       LD16(d2[4],2304); LD16(d2[5],2320); LD16(d2[6],2432); LD16(d2[7],2448); \
                       LD16(d2[8],2560); LD16(d2[9],2576); LD16(d2[10],2688);LD16(d2[11],2704);\
                       LD16(d2[12],2816);LD16(d2[13],2832);LD16(d2[14],2944);LD16(d2[15],2960);}while(0)
#define ISSUE_G3() do{ LD16(d3[0],3072); LD16(d3[1],3088); LD16(d3[2],3200); LD16(d3[3],3216); \
                       LD16(d3[4],3328); LD16(d3[5],3344); LD16(d3[6],3456); LD16(d3[7],3472); \
                       LD16(d3[8],3584); LD16(d3[9],3600); LD16(d3[10],3712);LD16(d3[11],3728);\
                       LD16(d3[12],3840);LD16(d3[13],3856);LD16(d3[14],3968);LD16(d3[15],3984);}while(0)

#define VMCNT0() do{ asm volatile("s_waitcnt vmcnt(0)" ::: "memory");         \
                     __builtin_amdgcn_sched_barrier(0); }while(0)

__device__ __forceinline__ unsigned badof(const u32x4& v, unsigned tt) {
    return (v.x ^ tt) | (v.y ^ tt) | (v.z ^ tt) | (v.w ^ tt);
}

__device__ __forceinline__ unsigned group_bad(const u32x4* d, unsigned tt) {
    unsigned bad = 0;
    #pragma unroll
    for (int j = 0; j < 16; ++j) bad |= badof(d[j], tt);
    return bad;
}

// rare path: group's producers late -> re-issue just that group and re-wait
#define WAITFIX(dg, REISSUE) do{ int tries = 0;                               \
    while (__any((int)(group_bad(dg, tt) >> 16))) {                           \
        if (++tries > 100000) break;   /* fail loud, don't hang */            \
        __builtin_amdgcn_s_sleep(1);                                          \
        REISSUE();                                                            \
        VMCNT0();                                                             \
    } }while(0)

template<int G>
__device__ __forceinline__ void mfma_group(const u32x4* d,
        const unsigned short* wr, const unsigned short* wz, const unsigned short* wn,
        f32x4& ar, f32x4& az, f32x4& ahn) {
    #pragma unroll
    for (int kk = 0; kk < 8; ++kk) {
        const int ki = G * 8 + kk;
        u32x4 lo = d[2 * kk], hi = d[2 * kk + 1];
        union { unsigned u[4]; bf16x8 v; } a;
        // strip tags: pack low16 of word pairs -> bf16x8 in memory order
        a.u[0] = __builtin_amdgcn_perm(lo.y, lo.x, 0x05040100u);
        a.u[1] = __builtin_amdgcn_perm(lo.w, lo.z, 0x05040100u);
        a.u[2] = __builtin_amdgcn_perm(hi.y, hi.x, 0x05040100u);
        a.u[3] = __builtin_amdgcn_perm(hi.w, hi.z, 0x05040100u);
        bf16x8 br = *(const bf16x8*)&wr[ki * 32];
        bf16x8 bz = *(const bf16x8*)&wz[ki * 32];
        bf16x8 bn = *(const bf16x8*)&wn[ki * 32];
        ar  = __builtin_amdgcn_mfma_f32_16x16x32_bf16(a.v, br, ar, 0, 0, 0);
        az  = __builtin_amdgcn_mfma_f32_16x16x32_bf16(a.v, bz, az, 0, 0, 0);
        ahn = __builtin_amdgcn_mfma_f32_16x16x32_bf16(a.v, bn, ahn, 0, 0, 0);
    }
}

// ---------- persistent scan ----------
// 64 blocks, block g owns h columns [16g,16g+16). 4 waves, wave w = batches
// [16w,16w+16). Tagged data words, zero barriers in the main loop, waves
// fully decoupled. ABA safe: double buffer + transitive certification
// (writing tag t+2 requires having consumed all of h_{t+1}, which certifies
// every wave-plane consumed h_t).
__global__ __launch_bounds__(256, 1) void gru_scan(
    const unsigned short* __restrict__ xbf,
    const float* __restrict__ Wih,
    const float* __restrict__ mask,
    const float* __restrict__ init_h,
    const float* __restrict__ dmask,
    const float* __restrict__ Whh,
    const float* __restrict__ bih,
    const float* __restrict__ bhh,
    float* __restrict__ out,
    float* __restrict__ out_last,
    unsigned* __restrict__ hbuf32)       // 2 buffers of 64*1024 tagged words, zeroed
{
    __shared__ unsigned short wlds[48 * 1032];   // W_hh slice, rows r/z/n
    __shared__ unsigned short wxlds[48 * 520];   // W_ih slice

    const int g   = blockIdx.x;
    const int tid = threadIdx.x;
    const int w   = tid >> 6;
    const int l   = tid & 63;
    const int q   = l >> 4;          // k-quad
    const int c   = l & 15;          // n-col within block / m-row for A

    for (int idx = tid; idx < 48 * 1024; idx += 256) {
        int row = idx >> 10, col = idx & 1023;
        int sr = (row < 16) ? (g * 16 + row)
               : (row < 32) ? (H_ + g * 16 + row - 16)
                            : (2 * H_ + g * 16 + row - 32);
        wlds[row * 1032 + col] = f2bf(Whh[(size_t)sr * H_ + col]);
    }
    for (int idx = tid; idx < 48 * 512; idx += 256) {
        int row = idx >> 9, col = idx & 511;
        int sr = (row < 16) ? (g * 16 + row)
               : (row < 32) ? (H_ + g * 16 + row - 16)
                            : (2 * H_ + g * 16 + row - 32);
        wxlds[row * 520 + col] = f2bf(Wih[(size_t)sr * I_ + col]);
    }

    const int jd = g * 16 + c;
    const float b_r   = bih[jd] + bhh[jd];
    const float b_z   = bih[H_ + jd] + bhh[H_ + jd];
    const float bxn_b = bih[2 * H_ + jd];
    const float bhn_b = bhh[2 * H_ + jd];

    const int batch_A = w * 16 + c;

    float dm[4], hd[4], mc[4];
    int batch_C[4];
    #pragma unroll
    for (int r = 0; r < 4; ++r) {
        batch_C[r] = w * 16 + q * 4 + r;
        dm[r] = dmask[batch_C[r] * H_ + jd];
        float m1 = mask[batch_C[r] * S_ + 0];
        float h0 = init_h[batch_C[r] * H_ + jd];
        hd[r] = h0 * (dm[r] * m1 + 1.0f - m1);   // pre-dropped h for step 1
        mc[r] = m1;
        unsigned word = (1u << 16) | (unsigned)f2bf(hd[r]);   // tag = step 1
        __hip_atomic_store(&hbuf32[HWORDS + batch_C[r] * H_ + jd], word,
                           __ATOMIC_RELAXED, __HIP_MEMORY_SCOPE_AGENT);
    }
    __syncthreads();   // weights staged (the only barrier in this kernel)

    const int offx_r = c * 520,  offx_z = (16 + c) * 520,  offx_n = (32 + c) * 520;
    const unsigned short* wr = wlds + c * 1032 + q * 8;
    const unsigned short* wz = wlds + (16 + c) * 1032 + q * 8;
    const unsigned short* wn = wlds + (32 + c) * 1032 + q * 8;

    for (int t = 1; t <= S_; ++t) {
        const int s = t - 1;
        f32x4 ar, az, axn, ahn;
        #pragma unroll
        for (int r = 0; r < 4; ++r) { ar[r] = b_r; az[r] = b_z; axn[r] = bxn_b; ahn[r] = bhn_b; }

        float mn[4];
        if (t < S_) {
            #pragma unroll
            for (int r = 0; r < 4; ++r) mn[r] = mask[batch_C[r] * S_ + t];
        }

        // ---- x phase (h-independent; overlaps other blocks' h production) ----
        {
            const unsigned short* xp = xbf + (size_t)batch_A * (S_ * I_) + s * I_ + q * 8;
            #pragma unroll 4
            for (int ki = 0; ki < 16; ++ki) {
                bf16x8 a  = ld8(xp + ki * 32);
                bf16x8 br = *(const bf16x8*)&wxlds[offx_r + q * 8 + ki * 32];
                bf16x8 bz = *(const bf16x8*)&wxlds[offx_z + q * 8 + ki * 32];
                bf16x8 bn = *(const bf16x8*)&wxlds[offx_n + q * 8 + ki * 32];
                ar  = __builtin_amdgcn_mfma_f32_16x16x32_bf16(a, br, ar, 0, 0, 0);
                az  = __builtin_amdgcn_mfma_f32_16x16x32_bf16(a, bz, az, 0, 0, 0);
                axn = __builtin_amdgcn_mfma_f32_16x16x32_bf16(a, bn, axn, 0, 0, 0);
            }
        }

        // ---- h phase: issue ALL 64 loads (one RT), one wait, validate groups
        //      between MFMA batches; re-issue only a late group (rare) ----
        {
            const unsigned* hb = hbuf32 + (size_t)(t & 1) * HWORDS + batch_A * H_ + q * 8;
            const unsigned tt = (unsigned)t << 16;
            u32x4 d0[16], d1[16], d2[16], d3[16];
            ISSUE_G0(); ISSUE_G1(); ISSUE_G2(); ISSUE_G3();
            VMCNT0();
            WAITFIX(d0, ISSUE_G0);
            mfma_group<0>(d0, wr, wz, wn, ar, az, ahn);
            WAITFIX(d1, ISSUE_G1);
            mfma_group<1>(d1, wr, wz, wn, ar, az, ahn);
            WAITFIX(d2, ISSUE_G2);
            mfma_group<2>(d2, wr, wz, wn, ar, az, ahn);
            WAITFIX(d3, ISSUE_G3);
            mfma_group<3>(d3, wr, wz, wn, ar, az, ahn);
        }

        // ---- gates + state update ----
        #pragma unroll
        for (int r = 0; r < 4; ++r) {
            float rr = __builtin_amdgcn_rcpf(1.0f + __expf(-ar[r]));
            float zz = __builtin_amdgcn_rcpf(1.0f + __expf(-az[r]));
            float narg = axn[r] + rr * ahn[r];
            float E = __expf(-2.0f * fabsf(narg));
            float nn = copysignf((1.0f - E) * __builtin_amdgcn_rcpf(1.0f + E), narg);
            float m = mc[r];
            float curr = (1.0f - zz) * nn + zz * hd[r];
            float hnew = m * curr + (1.0f - m) * hd[r];
            out[((size_t)batch_C[r] * S_ + s) * H_ + jd] = hnew;
            if (t < S_) {
                hd[r] = hnew * (dm[r] * mn[r] + 1.0f - mn[r]);   // pre-drop for t+1
                mc[r] = mn[r];
                unsigned word = ((unsigned)(t + 1) << 16) | (unsigned)f2bf(hd[r]);
                __hip_atomic_store(&hbuf32[(size_t)((t + 1) & 1) * HWORDS
                                           + batch_C[r] * H_ + jd],
                                   word, __ATOMIC_RELAXED, __HIP_MEMORY_SCOPE_AGENT);
            } else {
                out_last[batch_C[r] * H_ + jd] = hnew;
            }
        }
        // pin the tagged stores here (they're the other blocks' critical path)
        asm volatile("" ::: "memory");
    }
}

extern "C" void kernel_launch(void* const* d_in, const int* in_sizes, int n_in,
                              void* d_out, int out_size, void* d_ws, size_t ws_size,
                              hipStream_t stream) {
    (void)in_sizes; (void)n_in; (void)out_size; (void)ws_size;
    const float* x     = (const float*)d_in[0];
    const float* mask  = (const float*)d_in[1];
    const float* inith = (const float*)d_in[2];
    const float* dmask = (const float*)d_in[3];
    const float* Wih   = (const float*)d_in[4];
    const float* Whh   = (const float*)d_in[5];
    const float* bih   = (const float*)d_in[6];
    const float* bhh   = (const float*)d_in[7];
    float* out      = (float*)d_out;
    float* out_last = out + (size_t)B_ * S_ * H_;

    char* ws = (char*)d_ws;
    unsigned* hbuf32    = (unsigned*)ws;                     // 512 KB (2x tagged h)
    unsigned short* xbf = (unsigned short*)(ws + 524288);    // 32 MB

    hipMemsetAsync(ws, 0, 524288, stream);                   // tags <- 0
    gru_prep<<<2048, 256, 0, stream>>>(x, xbf);
    gru_scan<<<NB, 256, 0, stream>>>(xbf, Wih, mask, inith, dmask, Whh, bih, bhh,
                                     out, out_last, hbuf32);
}

// Round 3
// 6195.306 us; speedup vs baseline: 1.2780x; 1.2780x over previous
//
#include <hip/hip_runtime.h>
#include <hip/hip_bf16.h>
#include <stdint.h>

#define B_ 64
#define S_ 512
#define I_ 512
#define H_ 1024
#define NB 64          // blocks; block g owns 16 h-columns [16g, 16g+16)
#define HWORDS (B_ * H_)   // 65536 words per h buffer

typedef __attribute__((ext_vector_type(8))) __bf16 bf16x8;
typedef __attribute__((ext_vector_type(4))) float f32x4;
typedef __attribute__((ext_vector_type(4))) unsigned u32x4;

__device__ __forceinline__ unsigned short f2bf(float f) {
    unsigned u = __float_as_uint(f);
    u += 0x7FFFu + ((u >> 16) & 1u);   // RNE
    return (unsigned short)(u >> 16);
}

__device__ __forceinline__ bf16x8 ld8(const unsigned short* p) {
    return *(const bf16x8*)p;
}

// CACHED 16B load (hits L1/L2). Round 8 change: the h exchange has 64x read
// amplification (every block reads the full h); rounds 0-2 all bypassed L2
// (sc0 sc1) and all plateaued at ~16k uncached mall requests/step = 12us/step
// -> the floor is mall REQUEST THROUGHPUT, not protocol or latency. Cached
// loads let the 8 blocks of an XCD share one L2 refill (8x fewer mall
// transactions); per-word tags make stale L1/L2 data always DETECTED (then
// fence+retry), never trusted.
__device__ __forceinline__ void ld16_c(u32x4& d, const unsigned* p) {
    asm volatile("global_load_dwordx4 %0, %1, off" : "=v"(d) : "v"(p));
}

// ---------- prep: convert x to bf16 ----------
__global__ __launch_bounds__(256) void gru_prep(const float* __restrict__ x,
                                                unsigned short* __restrict__ xbf) {
    const int NX = (B_ * S_ * I_) / 4;
    int stride = gridDim.x * blockDim.x;
    for (int i = blockIdx.x * blockDim.x + threadIdx.x; i < NX; i += stride) {
        float4 v = ((const float4*)x)[i];
        ushort4 o;
        o.x = f2bf(v.x); o.y = f2bf(v.y); o.z = f2bf(v.z); o.w = f2bf(v.w);
        ((ushort4*)xbf)[i] = o;
    }
}

// ---------- tagged-exchange helpers ----------
// h words are (step_tag<<16)|bf16(h): self-validating, so no flags, no
// producer drain, no barriers, and no load-ordering requirements (tag and
// data share one 4B word). Group = 8 K-chunks = 16 dwordx4 = 256 cols... of
// this wave's 16 batch rows (cols [G*256, G*256+256) => producer blocks
// [16G, 16G+16)).
template<int G4>
__device__ __forceinline__ void issue_group(u32x4* d, const unsigned* hb) {
    const unsigned* p = hb + G4 * 256;
    #pragma unroll
    for (int kk = 0; kk < 8; ++kk) {
        ld16_c(d[2 * kk],     p + kk * 32);
        ld16_c(d[2 * kk + 1], p + kk * 32 + 4);
    }
    __builtin_amdgcn_sched_barrier(0);   // keep issues ahead of following MFMAs
}

__device__ __forceinline__ unsigned badof(const u32x4& v, unsigned tt) {
    return (v.x ^ tt) | (v.y ^ tt) | (v.z ^ tt) | (v.w ^ tt);
}

template<int G4>
__device__ __forceinline__ void wait_group(u32x4* d, const unsigned* hb, unsigned tt) {
    asm volatile("s_waitcnt vmcnt(0)" ::: "memory");
    __builtin_amdgcn_sched_barrier(0);   // rule #18: block hoisting past the wait
    int tries = 0;
    for (;;) {
        unsigned bad = 0;
        #pragma unroll
        for (int j = 0; j < 16; ++j) bad |= badof(d[j], tt);
        if (!__any((int)(bad >> 16))) return;      // all 256 tags == t
        if (++tries > 100000) return;              // fail loud, don't hang
        __builtin_amdgcn_s_sleep(1);
        // stale L1/L2 line: invalidate this XCD's caches, refetch from mall.
        // Fresh data then serves the XCD's other 7 blocks as L2 hits.
        __builtin_amdgcn_fence(__ATOMIC_ACQUIRE, "agent");
        issue_group<G4>(d, hb);
        asm volatile("s_waitcnt vmcnt(0)" ::: "memory");
        __builtin_amdgcn_sched_barrier(0);
    }
}

template<int G>
__device__ __forceinline__ void mfma_group(const u32x4* d,
        const unsigned short* wr, const unsigned short* wz, const unsigned short* wn,
        f32x4& ar, f32x4& az, f32x4& ahn) {
    #pragma unroll
    for (int kk = 0; kk < 8; ++kk) {
        const int ki = G * 8 + kk;
        u32x4 lo = d[2 * kk], hi = d[2 * kk + 1];
        union { unsigned u[4]; bf16x8 v; } a;
        // strip tags: pack low16 of word pairs -> bf16x8 in memory order
        a.u[0] = __builtin_amdgcn_perm(lo.y, lo.x, 0x05040100u);
        a.u[1] = __builtin_amdgcn_perm(lo.w, lo.z, 0x05040100u);
        a.u[2] = __builtin_amdgcn_perm(hi.y, hi.x, 0x05040100u);
        a.u[3] = __builtin_amdgcn_perm(hi.w, hi.z, 0x05040100u);
        bf16x8 br = *(const bf16x8*)&wr[ki * 32];
        bf16x8 bz = *(const bf16x8*)&wz[ki * 32];
        bf16x8 bn = *(const bf16x8*)&wn[ki * 32];
        ar  = __builtin_amdgcn_mfma_f32_16x16x32_bf16(a.v, br, ar, 0, 0, 0);
        az  = __builtin_amdgcn_mfma_f32_16x16x32_bf16(a.v, bz, az, 0, 0, 0);
        ahn = __builtin_amdgcn_mfma_f32_16x16x32_bf16(a.v, bn, ahn, 0, 0, 0);
    }
}

// ---------- persistent scan ----------
// 64 blocks, block g owns h columns [16g,16g+16). 4 waves, wave w = batches
// [16w,16w+16). Tagged data words, zero barriers in the main loop, waves
// fully decoupled. ABA safe: double buffer + transitive certification
// (writing tag t+2 requires having consumed all of h_{t+1}, which certifies
// every wave-plane consumed h_t).
__global__ __launch_bounds__(256, 1) void gru_scan(
    const unsigned short* __restrict__ xbf,
    const float* __restrict__ Wih,
    const float* __restrict__ mask,
    const float* __restrict__ init_h,
    const float* __restrict__ dmask,
    const float* __restrict__ Whh,
    const float* __restrict__ bih,
    const float* __restrict__ bhh,
    float* __restrict__ out,
    float* __restrict__ out_last,
    unsigned* __restrict__ hbuf32)       // 2 buffers of 64*1024 tagged words, zeroed
{
    __shared__ unsigned short wlds[48 * 1032];   // W_hh slice, rows r/z/n
    __shared__ unsigned short wxlds[48 * 520];   // W_ih slice

    const int g   = blockIdx.x;
    const int tid = threadIdx.x;
    const int w   = tid >> 6;
    const int l   = tid & 63;
    const int q   = l >> 4;          // k-quad
    const int c   = l & 15;          // n-col within block / m-row for A

    for (int idx = tid; idx < 48 * 1024; idx += 256) {
        int row = idx >> 10, col = idx & 1023;
        int sr = (row < 16) ? (g * 16 + row)
               : (row < 32) ? (H_ + g * 16 + row - 16)
                            : (2 * H_ + g * 16 + row - 32);
        wlds[row * 1032 + col] = f2bf(Whh[(size_t)sr * H_ + col]);
    }
    for (int idx = tid; idx < 48 * 512; idx += 256) {
        int row = idx >> 9, col = idx & 511;
        int sr = (row < 16) ? (g * 16 + row)
               : (row < 32) ? (H_ + g * 16 + row - 16)
                            : (2 * H_ + g * 16 + row - 32);
        wxlds[row * 520 + col] = f2bf(Wih[(size_t)sr * I_ + col]);
    }

    const int jd = g * 16 + c;
    const float b_r   = bih[jd] + bhh[jd];
    const float b_z   = bih[H_ + jd] + bhh[H_ + jd];
    const float bxn_b = bih[2 * H_ + jd];
    const float bhn_b = bhh[2 * H_ + jd];

    const int batch_A = w * 16 + c;

    float dm[4], hd[4], mc[4];
    int batch_C[4];
    #pragma unroll
    for (int r = 0; r < 4; ++r) {
        batch_C[r] = w * 16 + q * 4 + r;
        dm[r] = dmask[batch_C[r] * H_ + jd];
        float m1 = mask[batch_C[r] * S_ + 0];
        float h0 = init_h[batch_C[r] * H_ + jd];
        hd[r] = h0 * (dm[r] * m1 + 1.0f - m1);   // pre-dropped h for step 1
        mc[r] = m1;
        unsigned word = (1u << 16) | (unsigned)f2bf(hd[r]);   // tag = step 1
        __hip_atomic_store(&hbuf32[HWORDS + batch_C[r] * H_ + jd], word,
                           __ATOMIC_RELAXED, __HIP_MEMORY_SCOPE_AGENT);
    }
    __syncthreads();   // weights staged (the only barrier in this kernel)

    const int offx_r = c * 520,  offx_z = (16 + c) * 520,  offx_n = (32 + c) * 520;
    const unsigned short* wr = wlds + c * 1032 + q * 8;
    const unsigned short* wz = wlds + (16 + c) * 1032 + q * 8;
    const unsigned short* wn = wlds + (32 + c) * 1032 + q * 8;

    for (int t = 1; t <= S_; ++t) {
        const int s = t - 1;
        f32x4 ar, az, axn, ahn;
        #pragma unroll
        for (int r = 0; r < 4; ++r) { ar[r] = b_r; az[r] = b_z; axn[r] = bxn_b; ahn[r] = bhn_b; }

        float mn[4];
        if (t < S_) {
            #pragma unroll
            for (int r = 0; r < 4; ++r) mn[r] = mask[batch_C[r] * S_ + t];
        }

        // ---- x phase (h-independent; overlaps other blocks' h production) ----
        {
            const unsigned short* xp = xbf + (size_t)batch_A * (S_ * I_) + s * I_ + q * 8;
            #pragma unroll 4
            for (int ki = 0; ki < 16; ++ki) {
                bf16x8 a  = ld8(xp + ki * 32);
                bf16x8 br = *(const bf16x8*)&wxlds[offx_r + q * 8 + ki * 32];
                bf16x8 bz = *(const bf16x8*)&wxlds[offx_z + q * 8 + ki * 32];
                bf16x8 bn = *(const bf16x8*)&wxlds[offx_n + q * 8 + ki * 32];
                ar  = __builtin_amdgcn_mfma_f32_16x16x32_bf16(a, br, ar, 0, 0, 0);
                az  = __builtin_amdgcn_mfma_f32_16x16x32_bf16(a, bz, az, 0, 0, 0);
                axn = __builtin_amdgcn_mfma_f32_16x16x32_bf16(a, bn, axn, 0, 0, 0);
            }
        }

        // ---- h phase: cached load-as-poll on tagged words, 4 pipelined groups,
        //      fence+reissue only on stale (leader pays mall RT, followers
        //      on the XCD hit fresh L2) ----
        {
            const unsigned* hb = hbuf32 + (size_t)(t & 1) * HWORDS + batch_A * H_ + q * 8;
            const unsigned tt = (unsigned)t << 16;
            u32x4 dA[16], dB[16];
            issue_group<0>(dA, hb);
            wait_group<0>(dA, hb, tt);       // absorbs nearly all waiting
            issue_group<1>(dB, hb);
            mfma_group<0>(dA, wr, wz, wn, ar, az, ahn);
            wait_group<1>(dB, hb, tt);
            issue_group<2>(dA, hb);
            mfma_group<1>(dB, wr, wz, wn, ar, az, ahn);
            wait_group<2>(dA, hb, tt);
            issue_group<3>(dB, hb);
            mfma_group<2>(dA, wr, wz, wn, ar, az, ahn);
            wait_group<3>(dB, hb, tt);
            mfma_group<3>(dB, wr, wz, wn, ar, az, ahn);
        }

        // ---- gates + state update ----
        #pragma unroll
        for (int r = 0; r < 4; ++r) {
            float rr = __builtin_amdgcn_rcpf(1.0f + __expf(-ar[r]));
            float zz = __builtin_amdgcn_rcpf(1.0f + __expf(-az[r]));
            float narg = axn[r] + rr * ahn[r];
            float E = __expf(-2.0f * fabsf(narg));
            float nn = copysignf((1.0f - E) * __builtin_amdgcn_rcpf(1.0f + E), narg);
            float m = mc[r];
            float curr = (1.0f - zz) * nn + zz * hd[r];
            float hnew = m * curr + (1.0f - m) * hd[r];
            out[((size_t)batch_C[r] * S_ + s) * H_ + jd] = hnew;
            if (t < S_) {
                hd[r] = hnew * (dm[r] * mn[r] + 1.0f - mn[r]);   // pre-drop for t+1
                mc[r] = mn[r];
                unsigned word = ((unsigned)(t + 1) << 16) | (unsigned)f2bf(hd[r]);
                __hip_atomic_store(&hbuf32[(size_t)((t + 1) & 1) * HWORDS
                                           + batch_C[r] * H_ + jd],
                                   word, __ATOMIC_RELAXED, __HIP_MEMORY_SCOPE_AGENT);
            } else {
                out_last[batch_C[r] * H_ + jd] = hnew;
            }
        }
        // pin the tagged stores here (they're the other blocks' critical path)
        asm volatile("" ::: "memory");
    }
}

extern "C" void kernel_launch(void* const* d_in, const int* in_sizes, int n_in,
                              void* d_out, int out_size, void* d_ws, size_t ws_size,
                              hipStream_t stream) {
    (void)in_sizes; (void)n_in; (void)out_size; (void)ws_size;
    const float* x     = (const float*)d_in[0];
    const float* mask  = (const float*)d_in[1];
    const float* inith = (const float*)d_in[2];
    const float* dmask = (const float*)d_in[3];
    const float* Wih   = (const float*)d_in[4];
    const float* Whh   = (const float*)d_in[5];
    const float* bih   = (const float*)d_in[6];
    const float* bhh   = (const float*)d_in[7];
    float* out      = (float*)d_out;
    float* out_last = out + (size_t)B_ * S_ * H_;

    char* ws = (char*)d_ws;
    unsigned* hbuf32    = (unsigned*)ws;                     // 512 KB (2x tagged h)
    unsigned short* xbf = (unsigned short*)(ws + 524288);    // 32 MB

    hipMemsetAsync(ws, 0, 524288, stream);                   // tags <- 0
    gru_prep<<<2048, 256, 0, stream>>>(x, xbf);
    gru_scan<<<NB, 256, 0, stream>>>(xbf, Wih, mask, inith, dmask, Whh, bih, bhh,
                                     out, out_last, hbuf32);
}

// Round 6
// 4364.852 us; speedup vs baseline: 1.8139x; 1.4194x over previous
//
#include <hip/hip_runtime.h>
#include <hip/hip_bf16.h>
#include <stdint.h>

#define B_ 64
#define S_ 512
#define I_ 512
#define H_ 1024
#define NB 64              // blocks; block g owns 16 h-columns [16g, 16g+16)
#define HWORDS (B_ * H_)   // 65536 bf16 per h buffer

typedef __attribute__((ext_vector_type(8))) __bf16 bf16x8;
typedef __attribute__((ext_vector_type(4))) float f32x4;
typedef __attribute__((ext_vector_type(4))) unsigned u32x4;

__device__ __forceinline__ unsigned short f2bf(float f) {
    unsigned u = __float_as_uint(f);
    u += 0x7FFFu + ((u >> 16) & 1u);   // RNE
    return (unsigned short)(u >> 16);
}

__device__ __forceinline__ bf16x8 ld8(const unsigned short* p) {
    return *(const bf16x8*)p;
}

// ---------- prep: convert x to bf16 ----------
__global__ __launch_bounds__(256) void gru_prep(const float* __restrict__ x,
                                                unsigned short* __restrict__ xbf) {
    const int NX = (B_ * S_ * I_) / 4;
    int stride = gridDim.x * blockDim.x;
    for (int i = blockIdx.x * blockDim.x + threadIdx.x; i < NX; i += stride) {
        float4 v = ((const float4*)x)[i];
        ushort4 o;
        o.x = f2bf(v.x); o.y = f2bf(v.y); o.z = f2bf(v.z); o.w = f2bf(v.w);
        ((ushort4*)xbf)[i] = o;
    }
}

// ---------- round-11 exchange (round-9 design; compile fix only) ----------
// Ledger: R0 flags+8MB/step=12.1us/step, R1 tags+16MB=11.9, R2 burst+retry=15.5,
// R3 fence=12.1, R4 no data (container), R5 compile error (s_sleep needs
// constant arg). Model: T = T_protocol + T_exchange(bytes); this design
// minimizes both: UNTAGGED bf16 (8MB/step) + per-WAVE-PLANE flags with
// wave-local release (no __syncthreads coupling) + certified-before-issue
// burst loads drained with COUNTED vmcnt between MFMA groups (no retry
// machinery).
//
// Ordering: producer wave w: h-stores -> s_waitcnt vmcnt(0) -> flag[w][g]=t+1
// (acks at mall before flag visible). Consumer wave w: poll its 64 plane-w
// flags (1 dword/lane, sc0 sc1) until all >= t, THEN issue data loads -> any
// read reaching the mall after flag-visibility sees the h-stores. ABA safe:
// double buffer + transitive certification (producing h_{t+2} into buf[t&1]
// requires having consumed h_{t+1}, which certifies every plane consumed h_t).

// 16B L2-bypassing load, literal byte offset (data certified, no tags needed)
#define LDH(dst, off) asm volatile(                                           \
    "global_load_dwordx4 %0, %1, off offset:" #off " sc0 sc1"                 \
    : "=v"(dst) : "v"(hp))

#define ISSUE_ALL() do{                                                       \
    LDH(d[0],0);     LDH(d[1],64);    LDH(d[2],128);   LDH(d[3],192);         \
    LDH(d[4],256);   LDH(d[5],320);   LDH(d[6],384);   LDH(d[7],448);         \
    LDH(d[8],512);   LDH(d[9],576);   LDH(d[10],640);  LDH(d[11],704);        \
    LDH(d[12],768);  LDH(d[13],832);  LDH(d[14],896);  LDH(d[15],960);        \
    LDH(d[16],1024); LDH(d[17],1088); LDH(d[18],1152); LDH(d[19],1216);       \
    LDH(d[20],1280); LDH(d[21],1344); LDH(d[22],1408); LDH(d[23],1472);       \
    LDH(d[24],1536); LDH(d[25],1600); LDH(d[26],1664); LDH(d[27],1728);       \
    LDH(d[28],1792); LDH(d[29],1856); LDH(d[30],1920); LDH(d[31],1984); }while(0)

#define WAITV(n) do{ asm volatile("s_waitcnt vmcnt(" #n ")" ::: "memory");    \
                     __builtin_amdgcn_sched_barrier(0); }while(0)

template<int G>
__device__ __forceinline__ void mfma_group(const u32x4* d,
        const unsigned short* wr, const unsigned short* wz, const unsigned short* wn,
        f32x4& ar, f32x4& az, f32x4& ahn) {
    #pragma unroll
    for (int kk = 0; kk < 8; ++kk) {
        const int ki = G * 8 + kk;
        union { u32x4 u; bf16x8 v; } a;
        a.u = d[ki];                       // raw bf16 fragment — no tag stripping
        bf16x8 br = *(const bf16x8*)&wr[ki * 32];
        bf16x8 bz = *(const bf16x8*)&wz[ki * 32];
        bf16x8 bn = *(const bf16x8*)&wn[ki * 32];
        ar  = __builtin_amdgcn_mfma_f32_16x16x32_bf16(a.v, br, ar, 0, 0, 0);
        az  = __builtin_amdgcn_mfma_f32_16x16x32_bf16(a.v, bz, az, 0, 0, 0);
        ahn = __builtin_amdgcn_mfma_f32_16x16x32_bf16(a.v, bn, ahn, 0, 0, 0);
    }
}

// ---------- persistent scan ----------
// 64 blocks, block g owns h columns [16g,16g+16). 4 waves, wave w = batches
// [16w,16w+16) = exactly the rows producer-wave w of every block writes, so
// the 4 wave-planes are fully independent pipelines (no barriers in the loop).
__global__ __launch_bounds__(256, 1) void gru_scan(
    const unsigned short* __restrict__ xbf,
    const float* __restrict__ Wih,
    const float* __restrict__ mask,
    const float* __restrict__ init_h,
    const float* __restrict__ dmask,
    const float* __restrict__ Whh,
    const float* __restrict__ bih,
    const float* __restrict__ bhh,
    float* __restrict__ out,
    float* __restrict__ out_last,
    unsigned* __restrict__ flags,        // [4 planes][64 blocks] dwords, zeroed
    unsigned short* __restrict__ hbuf16) // 2 buffers of 64*1024 bf16
{
    __shared__ unsigned short wlds[48 * 1032];   // W_hh slice, rows r/z/n
    __shared__ unsigned short wxlds[48 * 520];   // W_ih slice

    const int g   = blockIdx.x;
    const int tid = threadIdx.x;
    const int w   = tid >> 6;
    const int l   = tid & 63;
    const int q   = l >> 4;          // k-quad
    const int c   = l & 15;          // n-col within block / m-row for A

    for (int idx = tid; idx < 48 * 1024; idx += 256) {
        int row = idx >> 10, col = idx & 1023;
        int sr = (row < 16) ? (g * 16 + row)
               : (row < 32) ? (H_ + g * 16 + row - 16)
                            : (2 * H_ + g * 16 + row - 32);
        wlds[row * 1032 + col] = f2bf(Whh[(size_t)sr * H_ + col]);
    }
    for (int idx = tid; idx < 48 * 512; idx += 256) {
        int row = idx >> 9, col = idx & 511;
        int sr = (row < 16) ? (g * 16 + row)
               : (row < 32) ? (H_ + g * 16 + row - 16)
                            : (2 * H_ + g * 16 + row - 32);
        wxlds[row * 520 + col] = f2bf(Wih[(size_t)sr * I_ + col]);
    }

    const int jd = g * 16 + c;
    const float b_r   = bih[jd] + bhh[jd];
    const float b_z   = bih[H_ + jd] + bhh[H_ + jd];
    const float bxn_b = bih[2 * H_ + jd];
    const float bhn_b = bhh[2 * H_ + jd];

    const int batch_A = w * 16 + c;

    float dm[4], hd[4], mc[4];
    int batch_C[4];
    #pragma unroll
    for (int r = 0; r < 4; ++r) {
        batch_C[r] = w * 16 + q * 4 + r;
        dm[r] = dmask[batch_C[r] * H_ + jd];
        float m1 = mask[batch_C[r] * S_ + 0];
        float h0 = init_h[batch_C[r] * H_ + jd];
        hd[r] = h0 * (dm[r] * m1 + 1.0f - m1);   // pre-dropped h for step 1
        mc[r] = m1;
        __hip_atomic_store(&hbuf16[HWORDS + batch_C[r] * H_ + jd], f2bf(hd[r]),
                           __ATOMIC_RELAXED, __HIP_MEMORY_SCOPE_AGENT);
    }
    // wave-local release: this wave's h_1 stores acked at mall, then its flag
    asm volatile("s_waitcnt vmcnt(0)" ::: "memory");
    __builtin_amdgcn_sched_barrier(0);
    if (l == 0)
        __hip_atomic_store(&flags[w * 64 + g], 1u,
                           __ATOMIC_RELAXED, __HIP_MEMORY_SCOPE_AGENT);
    __syncthreads();   // weights staged (the only barrier in this kernel)

    const int offx_r = c * 520,  offx_z = (16 + c) * 520,  offx_n = (32 + c) * 520;
    const unsigned short* wr = wlds + c * 1032 + q * 8;
    const unsigned short* wz = wlds + (16 + c) * 1032 + q * 8;
    const unsigned short* wn = wlds + (32 + c) * 1032 + q * 8;
    const unsigned* fp = flags + w * 64 + l;     // plane-w flag, one per lane

    for (int t = 1; t <= S_; ++t) {
        const int s = t - 1;
        f32x4 ar, az, axn, ahn;
        #pragma unroll
        for (int r = 0; r < 4; ++r) { ar[r] = b_r; az[r] = b_z; axn[r] = bxn_b; ahn[r] = bhn_b; }

        float mn[4];
        if (t < S_) {
            #pragma unroll
            for (int r = 0; r < 4; ++r) mn[r] = mask[batch_C[r] * S_ + t];
        }

        // ---- x phase (h-independent; overlaps other blocks' h production) ----
        {
            const unsigned short* xp = xbf + (size_t)batch_A * (S_ * I_) + s * I_ + q * 8;
            #pragma unroll 4
            for (int ki = 0; ki < 16; ++ki) {
                bf16x8 a  = ld8(xp + ki * 32);
                bf16x8 br = *(const bf16x8*)&wxlds[offx_r + q * 8 + ki * 32];
                bf16x8 bz = *(const bf16x8*)&wxlds[offx_z + q * 8 + ki * 32];
                bf16x8 bn = *(const bf16x8*)&wxlds[offx_n + q * 8 + ki * 32];
                ar  = __builtin_amdgcn_mfma_f32_16x16x32_bf16(a, br, ar, 0, 0, 0);
                az  = __builtin_amdgcn_mfma_f32_16x16x32_bf16(a, bz, az, 0, 0, 0);
                axn = __builtin_amdgcn_mfma_f32_16x16x32_bf16(a, bn, axn, 0, 0, 0);
            }
        }

        // ---- acquire: poll this plane's 64 flags (one dword load per lane).
        //      HARD spin cap (12k): a stalled plane terminates (wrong answer,
        //      loud) instead of hanging the harness. ----
        {
            int spins = 0;
            for (;;) {
                unsigned v;
                asm volatile("global_load_dword %0, %1, off sc0 sc1" : "=v"(v) : "v"(fp));
                asm volatile("s_waitcnt vmcnt(0)" ::: "memory");
                __builtin_amdgcn_sched_barrier(0);
                if (__all(v >= (unsigned)t)) break;
                if (++spins > 12000) break;        // bounded: ~ms, not seconds
                if (spins < 64) { __builtin_amdgcn_s_sleep(1); }
                else            { __builtin_amdgcn_s_sleep(4); }
            }
        }

        // ---- h phase: certified burst (32 dwordx4/lane), counted-vmcnt drain ----
        {
            const unsigned short* hp = hbuf16 + (size_t)(t & 1) * HWORDS
                                     + batch_A * H_ + q * 8;
            u32x4 d[32];
            __builtin_amdgcn_sched_barrier(0);
            ISSUE_ALL();
            WAITV(24); mfma_group<0>(d, wr, wz, wn, ar, az, ahn);
            WAITV(16); mfma_group<1>(d, wr, wz, wn, ar, az, ahn);
            WAITV(8);  mfma_group<2>(d, wr, wz, wn, ar, az, ahn);
            WAITV(0);  mfma_group<3>(d, wr, wz, wn, ar, az, ahn);
        }

        // ---- gates ----
        float hnw[4];
        #pragma unroll
        for (int r = 0; r < 4; ++r) {
            float rr = __builtin_amdgcn_rcpf(1.0f + __expf(-ar[r]));
            float zz = __builtin_amdgcn_rcpf(1.0f + __expf(-az[r]));
            float narg = axn[r] + rr * ahn[r];
            float E = __expf(-2.0f * fabsf(narg));
            float nn = copysignf((1.0f - E) * __builtin_amdgcn_rcpf(1.0f + E), narg);
            float m = mc[r];
            float curr = (1.0f - zz) * nn + zz * hd[r];
            hnw[r] = m * curr + (1.0f - m) * hd[r];
        }

        if (t < S_) {
            // critical path first: h_{t+1} stores -> wave-local release -> flag
            #pragma unroll
            for (int r = 0; r < 4; ++r) {
                hd[r] = hnw[r] * (dm[r] * mn[r] + 1.0f - mn[r]);   // pre-drop t+1
                mc[r] = mn[r];
                __hip_atomic_store(&hbuf16[(size_t)((t + 1) & 1) * HWORDS
                                           + batch_C[r] * H_ + jd],
                                   f2bf(hd[r]),
                                   __ATOMIC_RELAXED, __HIP_MEMORY_SCOPE_AGENT);
            }
            asm volatile("s_waitcnt vmcnt(0)" ::: "memory");
            __builtin_amdgcn_sched_barrier(0);
            if (l == 0)
                __hip_atomic_store(&flags[w * 64 + g], (unsigned)(t + 1),
                                   __ATOMIC_RELAXED, __HIP_MEMORY_SCOPE_AGENT);
            // out[] stores AFTER the flag: off the inter-block critical path
            #pragma unroll
            for (int r = 0; r < 4; ++r)
                out[((size_t)batch_C[r] * S_ + s) * H_ + jd] = hnw[r];
        } else {
            #pragma unroll
            for (int r = 0; r < 4; ++r) {
                out[((size_t)batch_C[r] * S_ + s) * H_ + jd] = hnw[r];
                out_last[batch_C[r] * H_ + jd] = hnw[r];
            }
        }
        asm volatile("" ::: "memory");
    }
}

extern "C" void kernel_launch(void* const* d_in, const int* in_sizes, int n_in,
                              void* d_out, int out_size, void* d_ws, size_t ws_size,
                              hipStream_t stream) {
    (void)in_sizes; (void)n_in; (void)out_size; (void)ws_size;
    const float* x     = (const float*)d_in[0];
    const float* mask  = (const float*)d_in[1];
    const float* inith = (const float*)d_in[2];
    const float* dmask = (const float*)d_in[3];
    const float* Wih   = (const float*)d_in[4];
    const float* Whh   = (const float*)d_in[5];
    const float* bih   = (const float*)d_in[6];
    const float* bhh   = (const float*)d_in[7];
    float* out      = (float*)d_out;
    float* out_last = out + (size_t)B_ * S_ * H_;

    char* ws = (char*)d_ws;
    unsigned* flags       = (unsigned*)ws;                         // 1KB used, 8KB pad
    unsigned short* hbuf  = (unsigned short*)(ws + 8192);          // 256KB (2x h bf16)
    unsigned short* xbf   = (unsigned short*)(ws + 8192 + 262144); // 32MB

    (void)hipMemsetAsync(ws, 0, 8192, stream);                     // flags <- 0
    gru_prep<<<2048, 256, 0, stream>>>(x, xbf);
    gru_scan<<<NB, 256, 0, stream>>>(xbf, Wih, mask, inith, dmask, Whh, bih, bhh,
                                     out, out_last, flags, hbuf);
}